// Round 1
// 759.731 us; speedup vs baseline: 1.0368x; 1.0368x over previous
//
#include <hip/hip_runtime.h>
#include <hip/hip_bf16.h>
#include <cmath>

#define B_ 4
#define S_ 2048
#define D_ 1024
#define H_ 16
#define DH_ 64

typedef __attribute__((ext_vector_type(8))) short short8;
typedef __attribute__((ext_vector_type(4))) float f32x4;
#define MFMA_BF16(a, b, c) __builtin_amdgcn_mfma_f32_16x16x32_bf16(a, b, c, 0, 0, 0)

static __device__ __forceinline__ float b2f(unsigned short u) {
  union { unsigned int i; float f; } x; x.i = ((unsigned int)u) << 16; return x.f;
}
static __device__ __forceinline__ unsigned short f2b(float f) {
  union { float f; unsigned int i; } x; x.f = f;
  unsigned int r = x.i + 0x7FFFu + ((x.i >> 16) & 1u);
  return (unsigned short)(r >> 16);
}
// packed 2x f32 -> 2x bf16 (RNE), low = a
static __device__ __forceinline__ unsigned int pk2(float a, float b) {
  __hip_bfloat162 h = __float22bfloat162_rn(make_float2(a, b));
  return *(unsigned int*)&h;
}
// exact x mod 96 for 0 <= x < ~1e6
static __device__ __forceinline__ int mod96(int x) {
  int t = x >> 5;
  int q = (t * 43691) >> 17;  // floor(t/3), exact for t < 32768
  int m3 = t - q * 3;
  return (x & 31) + (m3 << 5);
}
// async global->LDS, 16B per lane; lds dest must be wave-uniform base (+lane*16)
typedef __attribute__((address_space(3))) unsigned int lds_u32_t;
typedef __attribute__((address_space(1))) const unsigned int glb_u32_t;
static __device__ __forceinline__ void gload_lds16(const void* g, void* l) {
  __builtin_amdgcn_global_load_lds((glb_u32_t*)g, (lds_u32_t*)l, 16, 0, 0);
}

// ---------------- LayerNorm -> bf16 ----------------
__global__ __launch_bounds__(256) void ln_kernel(const float* __restrict__ in,
                                                 const float* __restrict__ gamma,
                                                 const float* __restrict__ beta,
                                                 unsigned short* __restrict__ out) {
  int row = blockIdx.x;
  const float4* r4 = (const float4*)(in + (size_t)row * D_);
  float4 val = r4[threadIdx.x];
  float s = val.x + val.y + val.z + val.w;
  float sq = val.x * val.x + val.y * val.y + val.z * val.z + val.w * val.w;
#pragma unroll
  for (int o = 32; o > 0; o >>= 1) {
    s += __shfl_down(s, o);
    sq += __shfl_down(sq, o);
  }
  __shared__ float wsum[4], wsq[4];
  __shared__ float smu, srs;
  int wid = threadIdx.x >> 6;
  if ((threadIdx.x & 63) == 0) { wsum[wid] = s; wsq[wid] = sq; }
  __syncthreads();
  if (threadIdx.x == 0) {
    float ts = wsum[0] + wsum[1] + wsum[2] + wsum[3];
    float tq = wsq[0] + wsq[1] + wsq[2] + wsq[3];
    float mu = ts * (1.0f / D_);
    float var = tq * (1.0f / D_) - mu * mu;
    smu = mu;
    srs = rsqrtf(var + 1e-5f);
  }
  __syncthreads();
  float mu = smu, rs = srs;
  float4 g = ((const float4*)gamma)[threadIdx.x];
  float4 be = ((const float4*)beta)[threadIdx.x];
  ushort4 o;
  o.x = f2b((val.x - mu) * rs * g.x + be.x);
  o.y = f2b((val.y - mu) * rs * g.y + be.y);
  o.z = f2b((val.z - mu) * rs * g.z + be.z);
  o.w = f2b((val.w - mu) * rs * g.w + be.w);
  *(ushort4*)(out + (size_t)row * D_ + threadIdx.x * 4) = o;
}

// ---------------- fp32 -> bf16 cast ----------------
__global__ __launch_bounds__(256) void cast_kernel(const float* __restrict__ in,
                                                   unsigned short* __restrict__ out) {
  size_t idx = (size_t)(blockIdx.x * 256 + threadIdx.x) * 4;
  float4 v = *(const float4*)(in + idx);
  ushort4 o; o.x = f2b(v.x); o.y = f2b(v.y); o.z = f2b(v.z); o.w = f2b(v.w);
  *(ushort4*)(out + idx) = o;
}

// ---------------- Sinusoidal PE -> bf16 ----------------
// f64 angle + mod-2pi reduction, then f32 sincos (output is bf16; trig err ~1e-7
// vs bf16 quantization 4e-3 -> invisible). Avoids f64 software sin/cos.
__global__ __launch_bounds__(256) void pe_kernel(unsigned short* __restrict__ pe) {
  int idx = blockIdx.x * 256 + threadIdx.x;  // [0, S*D/2)
  int t = idx >> 9;
  int i = idx & 511;
  double div = exp(-(log(10000.0) * (2.0 * i) / (double)D_));
  double ang = (double)t * div;
  double k = floor(ang * 0.15915494309189535);   // 1/(2*pi)
  float red = (float)(ang - k * 6.283185307179586);
  ushort2 sc;
  sc.x = f2b(sinf(red));
  sc.y = f2b(cosf(red));
  *(ushort2*)(pe + (size_t)t * D_ + 2 * i) = sc;
}

// ---------------- W[K,N] fp32 -> WT[N,K] bf16 (64x64 tiles) ----------------
__global__ __launch_bounds__(256) void wtrans_kernel(const float* __restrict__ W,
                                                     unsigned short* __restrict__ WT) {
  __shared__ float t[64][65];
  int k0 = blockIdx.y * 64, n0 = blockIdx.x * 64;
  int tid = threadIdx.x;
#pragma unroll
  for (int c = 0; c < 4; c++) {
    int idx = tid + c * 256;          // 0..1023
    int r = idx >> 4;                 // 0..63
    int ch = (idx & 15) * 4;          // 0..60
    float4 d = *(const float4*)(W + (size_t)(k0 + r) * D_ + n0 + ch);
    t[r][ch] = d.x; t[r][ch + 1] = d.y; t[r][ch + 2] = d.z; t[r][ch + 3] = d.w;
  }
  __syncthreads();
  {
    int n = tid >> 2;                 // 0..63
    int ch = (tid & 3) * 16;          // 0,16,32,48
    unsigned short tmp[8];
#pragma unroll
    for (int half = 0; half < 2; half++) {
#pragma unroll
      for (int e = 0; e < 8; e++) tmp[e] = f2b(t[ch + half * 8 + e][n]);
      *(short8*)(WT + (size_t)(n0 + n) * D_ + k0 + ch + half * 8) = *(short8*)tmp;
    }
  }
}

// ---------------- bf16 MFMA GEMM: C[M,N] = A[M,K] @ BT[N,K]^T + bias ----------------
// m97 recipe: linear [128][32] u16 LDS tiles, staged via global_load_lds width=16.
// chunk c (16B) -> row c>>2, u16 col (c&3)*8; LDS byte off = c*16 (linear, lane-ordered).
template <bool F32OUT>
__global__ __launch_bounds__(256) void gemm_bf16_t(const unsigned short* __restrict__ A,
                                                   const unsigned short* __restrict__ BT,
                                                   const float* __restrict__ bias,
                                                   void* __restrict__ Cv,
                                                   int M, int N, int K) {
  __shared__ __align__(16) unsigned short As[128 * 32];
  __shared__ __align__(16) unsigned short Bs[128 * 32];
  const int tid = threadIdx.x;
  const int wid = tid >> 6, lane = tid & 63, quad = lane >> 4, l15 = lane & 15;
  const int m0 = blockIdx.y * 128, n0 = blockIdx.x * 128;
  const int moff = (wid >> 1) * 64, noff = (wid & 1) * 64;
  f32x4 acc[4][4];
#pragma unroll
  for (int i = 0; i < 4; i++)
#pragma unroll
    for (int j = 0; j < 4; j++) acc[i][j] = (f32x4){0.f, 0.f, 0.f, 0.f};

  const int cb0 = wid * 64;            // wave-uniform chunk base, round 0
  const int c0 = cb0 + lane;           // this lane's chunk, round 0
  const int r0 = c0 >> 2, ch0 = (c0 & 3) * 8;
  const int c1 = c0 + 256;             // round 1
  const int r1 = c1 >> 2, ch1 = (c1 & 3) * 8;

  for (int k0 = 0; k0 < K; k0 += 32) {
    __syncthreads();
    gload_lds16(A + (size_t)(m0 + r0) * K + k0 + ch0, &As[cb0 * 8]);
    gload_lds16(BT + (size_t)(n0 + r0) * K + k0 + ch0, &Bs[cb0 * 8]);
    gload_lds16(A + (size_t)(m0 + r1) * K + k0 + ch1, &As[(cb0 + 256) * 8]);
    gload_lds16(BT + (size_t)(n0 + r1) * K + k0 + ch1, &Bs[(cb0 + 256) * 8]);
    __syncthreads();
    short8 af[4], bf[4];
#pragma unroll
    for (int i = 0; i < 4; i++)
      af[i] = *(const short8*)&As[(moff + i * 16 + l15) * 32 + quad * 8];
#pragma unroll
    for (int j = 0; j < 4; j++)
      bf[j] = *(const short8*)&Bs[(noff + j * 16 + l15) * 32 + quad * 8];
#pragma unroll
    for (int i = 0; i < 4; i++)
#pragma unroll
      for (int j = 0; j < 4; j++) acc[i][j] = MFMA_BF16(af[i], bf[j], acc[i][j]);
  }
#pragma unroll
  for (int i = 0; i < 4; i++) {
    int row = m0 + moff + i * 16 + quad * 4;
#pragma unroll
    for (int j = 0; j < 4; j++) {
      int col = n0 + noff + j * 16 + l15;
      float bb = bias ? bias[col] : 0.f;
#pragma unroll
      for (int g = 0; g < 4; g++) {
        if (F32OUT)
          ((float*)Cv)[(size_t)(row + g) * N + col] = acc[i][j][g] + bb;
        else
          ((unsigned short*)Cv)[(size_t)(row + g) * N + col] = f2b(acc[i][j][g] + bb);
      }
    }
  }
}

// ---------------- v[b,s,h,dh] -> vt[b,h,dh,s] ----------------
__global__ __launch_bounds__(256) void vtrans_kernel(const unsigned short* __restrict__ v,
                                                     unsigned short* __restrict__ vt) {
  __shared__ __align__(16) unsigned short t[64 * 72];
  int s0 = blockIdx.x * 64, h = blockIdx.y, b = blockIdx.z;
  int tid = threadIdx.x;
#pragma unroll
  for (int c = 0; c < 2; c++) {
    int idx = tid + c * 256;
    int r = idx >> 3, ch = (idx & 7) * 8;
    short8 d = *(const short8*)(v + (((size_t)b * S_ + s0 + r) * H_ + h) * DH_ + ch);
    *(short8*)&t[r * 72 + ch] = d;
  }
  __syncthreads();
  {
    int dh = tid >> 2, ch = tid & 3;
    unsigned short tmp[8];
#pragma unroll
    for (int half = 0; half < 2; half++) {
#pragma unroll
      for (int e = 0; e < 8; e++) tmp[e] = t[(ch * 16 + half * 8 + e) * 72 + dh];
      *(short8*)(vt + ((size_t)(b * H_ + h) * 64 + dh) * S_ + s0 + ch * 16 + half * 8) =
          *(short8*)tmp;
    }
  }
}

// ---------------- cw[h,r] = (v_bias - u_bias)_h . p[r,h,:] ----------------
__global__ __launch_bounds__(256) void cw_kernel(const unsigned short* __restrict__ p,
                                                 const float* __restrict__ ub,
                                                 const float* __restrict__ vb,
                                                 float* __restrict__ cw) {
  int idx = blockIdx.x * 256 + threadIdx.x;  // [0, H*S)
  int r = idx & (S_ - 1), h = idx >> 11;
  float s = 0.f;
#pragma unroll 8
  for (int c = 0; c < 64; c++)
    s += (vb[h * 64 + c] - ub[h * 64 + c]) * b2f(p[(size_t)r * D_ + h * 64 + c]);
  cw[idx] = s;
}

// ---------------- MFMA flash attention with rel-shift (transposed score) -------
// d=j-i: d<=0 -> (q_i+v).p[S-1+d]; d==1 -> 0; d>=2 -> (q_{i+1}+v).p[d-2]
// Score computed transposed (A=K rows, B=Q rows): each thread has FIXED i=wr0+l15,
// 4 consecutive j per ct -> vectorized band gather + packed b64 prob writes.
// Bands: 96-ring + 3 mirror guard cols (width 99). Phase-split jt loop.
// q fragments (band a0/a1 for w=0/1; content bq = w=0 frags) are loop-invariant ->
// hoisted to registers once (removes 4 ds_read_b128 per wave per jt).
__global__ __launch_bounds__(256) void attn_kernel(const unsigned short* __restrict__ q,
                                                   const unsigned short* __restrict__ kg,
                                                   const unsigned short* __restrict__ vtg,
                                                   const unsigned short* __restrict__ pg,
                                                   const float* __restrict__ ub,
                                                   const float* __restrict__ cw,
                                                   unsigned short* __restrict__ ctx) {
  const int i0 = blockIdx.x * 64;
  const int h = blockIdx.y;
  const int b = blockIdx.z;
  const int tid = threadIdx.x;
  const int wid = tid >> 6, lane = tid & 63, quad = lane >> 4, l15 = lane & 15;
  const int wr0 = wid * 16;
  const int ib = i0 >> 5;  // first mixed jt

  __shared__ __align__(16) unsigned short qsu[65 * 72];   // q+u rows i0..i0+64
  __shared__ __align__(16) unsigned short ks[32 * 72];    // K tile [j][dh]
  __shared__ __align__(16) unsigned short vts[64 * 40];   // V^T tile [dh][j]
  __shared__ __align__(16) unsigned short ps[32 * 72];    // staged p rows [n][dh]
  __shared__ __align__(16) unsigned short prb[64 * 40];   // probs [i][j] (also prologue scratch)
  __shared__ __align__(16) unsigned short bandA[64 * 99]; // ring (q_i+v).p[r], col r%96
  __shared__ __align__(16) unsigned short bandB[64 * 99]; // ring (q_{i+1}+v).p[r]

  const int srow = tid >> 3, sch = (tid & 7) * 8;  // 32x64 staging (K, p)
  const int vrow = tid >> 2, vch = (tid & 3) * 8;  // 64x32 staging (V^T)

  const unsigned short* kgp = kg + ((size_t)b * S_ * H_ + h) * DH_ + (size_t)srow * H_ * DH_ + sch;
  const unsigned short* vgp = vtg + ((size_t)(b * H_ + h) * 64 + vrow) * S_ + vch;
  const unsigned short* pgp = pg + h * 64 + sch;
  const float* cwh = cw + h * S_;

  // ---- stage q + u_bias ----
  for (int li = tid; li < 65 * 16; li += 256) {
    int r = li >> 4, c4 = (li & 15) * 4;
    int qi = i0 + r; if (qi > S_ - 1) qi = S_ - 1;
    ushort4 raw = *(const ushort4*)(q + (((size_t)b * S_ + qi) * H_ + h) * DH_ + c4);
    ushort4 o;
    o.x = f2b(b2f(raw.x) + ub[h * 64 + c4 + 0]);
    o.y = f2b(b2f(raw.y) + ub[h * 64 + c4 + 1]);
    o.z = f2b(b2f(raw.z) + ub[h * 64 + c4 + 2]);
    o.w = f2b(b2f(raw.w) + ub[h * 64 + c4 + 3]);
    *(ushort4*)&qsu[r * 72 + c4] = o;
  }
  __syncthreads();
  // ---- hoist loop-invariant q fragments to registers ----
  short8 qa00, qa01, qa10, qa11;
  {
    int aoff = (wr0 + l15) * 72 + quad * 8;
    qa00 = *(const short8*)&qsu[aoff];
    qa01 = *(const short8*)&qsu[aoff + 32];
    qa10 = *(const short8*)&qsu[aoff + 72];        // w=1: q rows shifted +1
    qa11 = *(const short8*)&qsu[aoff + 72 + 32];
  }

  // band MFMA for one staged 32-row p task; src has [n][72] layout
  auto band_compute = [&](const unsigned short* src, int w, int rhi) {
    int rbase = rhi - 31;
    short8 a0 = w ? qa10 : qa00;
    short8 a1 = w ? qa11 : qa01;
    unsigned short* band = w ? bandB : bandA;
#pragma unroll
    for (int ct = 0; ct < 2; ct++) {
      short8 b0 = *(const short8*)&src[(ct * 16 + l15) * 72 + quad * 8];
      short8 b1 = *(const short8*)&src[(ct * 16 + l15) * 72 + 32 + quad * 8];
      f32x4 acc = (f32x4){0.f, 0.f, 0.f, 0.f};
      acc = MFMA_BF16(a0, b0, acc);
      acc = MFMA_BF16(a1, b1, acc);
      int rr = rbase + ct * 16 + l15;
      int rcl = rr < 0 ? 0 : (rr > S_ - 1 ? S_ - 1 : rr);
      float wv = cwh[rcl];
      int col = mod96(rr + 960);
      int brow0 = wr0 + quad * 4;
      unsigned int v01 = pk2(acc[0] + wv, acc[1] + wv);
      unsigned int v23 = pk2(acc[2] + wv, acc[3] + wv);
      unsigned short e0 = (unsigned short)v01, e1 = (unsigned short)(v01 >> 16);
      unsigned short e2 = (unsigned short)v23, e3 = (unsigned short)(v23 >> 16);
      band[(brow0 + 0) * 99 + col] = e0;
      band[(brow0 + 1) * 99 + col] = e1;
      band[(brow0 + 2) * 99 + col] = e2;
      band[(brow0 + 3) * 99 + col] = e3;
      if (col < 3) {  // mirror guard for 4-wide reads
        band[(brow0 + 0) * 99 + col + 96] = e0;
        band[(brow0 + 1) * 99 + col + 96] = e1;
        band[(brow0 + 2) * 99 + col + 96] = e2;
        band[(brow0 + 3) * 99 + col + 96] = e3;
      }
    }
  };

  // ---- prologue: 3 A backfills + 2 B backfills (ps + prb as scratch slots) ----
  {
    int TW[5] = {0, 0, 0, 1, 1};
    int TR[5] = {S_ + 30 - i0 - 64, S_ + 30 - i0 - 32, S_ + 30 - i0, 29, 61};
    for (int t0 = 0; t0 < 5; t0 += 2) {
      if (t0) __syncthreads();
      {
        int rr = TR[t0] - 31 + srow;
        int rc = rr < 0 ? 0 : (rr > S_ - 1 ? S_ - 1 : rr);
        *(short8*)&ps[srow * 72 + sch] = *(const short8*)(pgp + (size_t)rc * D_);
      }
      if (t0 + 1 < 5) {
        int rr = TR[t0 + 1] - 31 + srow;
        int rc = rr < 0 ? 0 : (rr > S_ - 1 ? S_ - 1 : rr);
        *(short8*)&prb[srow * 72 + sch] = *(const short8*)(pgp + (size_t)rc * D_);
      }
      if (t0 == 0) {
        *(short8*)&ks[srow * 72 + sch] = *(const short8*)kgp;
        *(short8*)&vts[vrow * 40 + vch] = *(const short8*)vgp;
      }
      __syncthreads();
      band_compute(ps, TW[t0], TR[t0]);
      if (t0 + 1 < 5) band_compute(prb, TW[t0 + 1], TR[t0 + 1]);
    }
    __syncthreads();
  }

  float lsum = 0.f;  // per thread: i = i0 + wr0 + l15 fixed
  f32x4 Oa[4];
#pragma unroll
  for (int ct = 0; ct < 4; ct++) Oa[ct] = (f32x4){0.f, 0.f, 0.f, 0.f};

  // incremental band ring columns (g=0, ct=0 element), advance +32 mod 96 / jt
  int cA = mod96(S_ - 1 + quad * 4 - i0 - wr0 - l15);           // >= 0
  int cB = mod96(2112 - 2 + quad * 4 - i0 - wr0 - l15);
  int cwin = 0, crhi = 0, chave = 0;  // task staged for current jt

  const float SCL = 0.03125f;
  const int browA = (wr0 + l15) * 99;
  const unsigned int prbw = (wr0 + l15) * 40 + quad * 4;  // u16 index, b64-aligned

  for (int jt = 0; jt < 64; jt++) {
    const int j0 = jt * 32;
    // ---- prefetch tile jt+1 into registers ----
    short8 pf_k, pf_v, pf_p;
    int pwin = 0, prhi = 0, havep = 0;
    {
      int j0n = (jt < 63) ? j0 + 32 : j0;
      pf_k = *(const short8*)(kgp + (size_t)j0n * (H_ * DH_));
      pf_v = *(const short8*)(vgp + j0n);
      int j0x = j0 + 32;
      if (j0x <= i0 + 63) { pwin = 0; prhi = S_ + 30 - i0 + j0x; havep = 1; }
      else if (jt < 63)   { pwin = 1; prhi = j0x - i0 + 29;      havep = 1; }
      if (havep) {
        int rr = prhi - 31 + srow;
        int rc = rr < 0 ? 0 : (rr > S_ - 1 ? S_ - 1 : rr);
        pf_p = *(const short8*)(pgp + (size_t)rc * D_);
      }
    }
    // ---- band MFMA for the task staged at jt-1 ----
    if (chave) band_compute(ps, cwin, crhi);
    // ---- content MFMA, transposed: Sc^T rows=j, cols=i ----
    f32x4 cc[2];
    {
#pragma unroll
      for (int ct = 0; ct < 2; ct++) {
        short8 a0 = *(const short8*)&ks[(ct * 16 + l15) * 72 + quad * 8];
        short8 a1 = *(const short8*)&ks[(ct * 16 + l15) * 72 + 32 + quad * 8];
        f32x4 acc = (f32x4){0.f, 0.f, 0.f, 0.f};
        acc = MFMA_BF16(a0, qa00, acc);
        acc = MFMA_BF16(a1, qa01, acc);
        cc[ct] = acc;
      }
    }
    // ---- score: thread = (i fixed, j = j0 + ct*16 + quad*4 + g) ----
    if (jt < ib) {
      // pure region A: t = bandA[i][r], r consecutive
#pragma unroll
      for (int ct = 0; ct < 2; ct++) {
        int c0 = ct ? (cA + 16 >= 96 ? cA + 16 - 96 : cA + 16) : cA;
        const unsigned short* base = &bandA[browA + c0];
        float e0 = __expf((cc[ct][0] + b2f(base[0])) * SCL);
        float e1 = __expf((cc[ct][1] + b2f(base[1])) * SCL);
        float e2 = __expf((cc[ct][2] + b2f(base[2])) * SCL);
        float e3 = __expf((cc[ct][3] + b2f(base[3])) * SCL);
        *(uint2*)&prb[prbw + ct * 16] = make_uint2(pk2(e0, e1), pk2(e2, e3));
        lsum += (e0 + e1) + (e2 + e3);
      }
    } else if (jt >= ib + 3) {
      // pure region B
#pragma unroll
      for (int ct = 0; ct < 2; ct++) {
        int c0 = ct ? (cB + 16 >= 96 ? cB + 16 - 96 : cB + 16) : cB;
        const unsigned short* base = &bandB[browA + c0];
        float e0 = __expf((cc[ct][0] + b2f(base[0])) * SCL);
        float e1 = __expf((cc[ct][1] + b2f(base[1])) * SCL);
        float e2 = __expf((cc[ct][2] + b2f(base[2])) * SCL);
        float e3 = __expf((cc[ct][3] + b2f(base[3])) * SCL);
        *(uint2*)&prb[prbw + ct * 16] = make_uint2(pk2(e0, e1), pk2(e2, e3));
        lsum += (e0 + e1) + (e2 + e3);
      }
    } else {
      // mixed: generic per element
#pragma unroll
      for (int ct = 0; ct < 2; ct++) {
        int jbase = j0 + ct * 16 + quad * 4;
        float ev[4];
#pragma unroll
        for (int g = 0; g < 4; g++) {
          int d = jbase + g - (i0 + wr0 + l15);
          float t;
          if (d == 1) t = 0.f;
          else {
            int rr = (d <= 0) ? (S_ - 1 + d) : (d - 2);
            const unsigned short* band = (d <= 0) ? bandA : bandB;
            t = b2f(band[browA + mod96(rr)]);
          }
          ev[g] = __expf((cc[ct][g] + t) * SCL);
          lsum += ev[g];
        }
        *(uint2*)&prb[prbw + ct * 16] = make_uint2(pk2(ev[0], ev[1]), pk2(ev[2], ev[3]));
      }
    }
    // ---- PV MFMA: O[i 16][dh 64] += P(16x32) @ V(32x64), prb wave-local ----
    {
      short8 af = *(const short8*)&prb[(wr0 + l15) * 40 + quad * 8];
#pragma unroll
      for (int ct = 0; ct < 4; ct++) {
        short8 bf = *(const short8*)&vts[(ct * 16 + l15) * 40 + quad * 8];
        Oa[ct] = MFMA_BF16(af, bf, Oa[ct]);
      }
    }
    // ---- commit prefetched tile jt+1 ----
    __syncthreads();
    *(short8*)&ks[srow * 72 + sch] = pf_k;
    *(short8*)&vts[vrow * 40 + vch] = pf_v;
    if (havep) *(short8*)&ps[srow * 72 + sch] = pf_p;
    cwin = pwin; crhi = prhi; chave = havep;
    __syncthreads();
    cA += 32; if (cA >= 96) cA -= 96;
    cB += 32; if (cB >= 96) cB -= 96;
  }
  // ---- epilogue ----
  float ltot = lsum;
  ltot += __shfl_xor(ltot, 16);
  ltot += __shfl_xor(ltot, 32);
#pragma unroll
  for (int g = 0; g < 4; g++) {
    float lg = __shfl(ltot, quad * 4 + g);  // holder lane for row quad*4+g
    float inv = 1.f / lg;
    int i = i0 + wr0 + quad * 4 + g;
    unsigned short* dst = ctx + ((size_t)b * S_ + i) * D_ + h * 64;
#pragma unroll
    for (int ct = 0; ct < 4; ct++) dst[ct * 16 + l15] = f2b(Oa[ct][g] * inv);
  }
}

extern "C" void kernel_launch(void* const* d_in, const int* in_sizes, int n_in,
                              void* d_out, int out_size, void* d_ws, size_t ws_size,
                              hipStream_t stream) {
  const float* inputs = (const float*)d_in[0];
  const float* pre_block = (const float*)d_in[1];
  const float* ln_gamma = (const float*)d_in[2];
  const float* ln_beta = (const float*)d_in[3];
  const float* Wq = (const float*)d_in[4];
  const float* bq = (const float*)d_in[5];
  const float* Wk = (const float*)d_in[6];
  const float* bk = (const float*)d_in[7];
  const float* Wv = (const float*)d_in[8];
  const float* bv = (const float*)d_in[9];
  const float* Wpos = (const float*)d_in[10];
  const float* u_bias = (const float*)d_in[11];
  const float* v_bias = (const float*)d_in[12];
  const float* Wo = (const float*)d_in[13];
  const float* bo = (const float*)d_in[14];
  float* out = (float*)d_out;

  char* ws = (char*)d_ws;
  const size_t NBS = (size_t)B_ * S_ * D_;  // 8388608
  unsigned short* xb = (unsigned short*)ws;                // NBS bf16
  unsigned short* ctx = (unsigned short*)ws;               // alias (xb dead after k-GEMM)
  unsigned short* preb = (unsigned short*)(ws + NBS * 2);  // NBS bf16
  unsigned short* peb = (unsigned short*)(ws + NBS * 4);   // S*D bf16
  char* base = ws + NBS * 4 + (size_t)S_ * D_ * 2;
  unsigned short* wtq = (unsigned short*)(base);
  unsigned short* wtk = (unsigned short*)(base + (size_t)D_ * D_ * 2);
  unsigned short* wtv = (unsigned short*)(base + (size_t)D_ * D_ * 4);
  unsigned short* wtp = (unsigned short*)(base + (size_t)D_ * D_ * 6);
  unsigned short* wto = (unsigned short*)(base + (size_t)D_ * D_ * 8);
  unsigned short* qb = (unsigned short*)(base + (size_t)D_ * D_ * 10);
  unsigned short* kb = qb + NBS;
  unsigned short* vb = kb + NBS;
  unsigned short* vtb = vb + NBS;
  unsigned short* pb = vtb + NBS;
  float* cww = (float*)(pb + (size_t)S_ * D_);

  ln_kernel<<<B_ * S_, 256, 0, stream>>>(inputs, ln_gamma, ln_beta, xb);
  cast_kernel<<<(int)(NBS / 1024), 256, 0, stream>>>(pre_block, preb);
  pe_kernel<<<(S_ * D_ / 2) / 256, 256, 0, stream>>>(peb);
  wtrans_kernel<<<dim3(16, 16), 256, 0, stream>>>(Wq, wtq);
  wtrans_kernel<<<dim3(16, 16), 256, 0, stream>>>(Wk, wtk);
  wtrans_kernel<<<dim3(16, 16), 256, 0, stream>>>(Wv, wtv);
  wtrans_kernel<<<dim3(16, 16), 256, 0, stream>>>(Wpos, wtp);
  wtrans_kernel<<<dim3(16, 16), 256, 0, stream>>>(Wo, wto);
  gemm_bf16_t<false><<<dim3(8, 64), 256, 0, stream>>>(xb, wtq, bq, qb, B_ * S_, D_, D_);
  gemm_bf16_t<false><<<dim3(8, 64), 256, 0, stream>>>(xb, wtk, bk, kb, B_ * S_, D_, D_);
  gemm_bf16_t<false><<<dim3(8, 64), 256, 0, stream>>>(preb, wtv, bv, vb, B_ * S_, D_, D_);
  gemm_bf16_t<false><<<dim3(8, 16), 256, 0, stream>>>(peb, wtp, nullptr, pb, S_, D_, D_);
  vtrans_kernel<<<dim3(32, 16, 4), 256, 0, stream>>>(vb, vtb);
  cw_kernel<<<(H_ * S_) / 256, 256, 0, stream>>>(pb, u_bias, v_bias, cww);
  attn_kernel<<<dim3(32, 16, 4), 256, 0, stream>>>(qb, kb, vtb, pb, u_bias, cww, ctx);
  gemm_bf16_t<true><<<dim3(8, 64), 256, 0, stream>>>(ctx, wto, bo, out, B_ * S_, D_, D_);
}